// Round 11
// baseline (268.054 us; speedup 1.0000x reference)
//
#include <hip/hip_runtime.h>
#include <hip/hip_bf16.h>

#define B_ 32
#define T_ 256
#define D_ 64
#define H_ 128
#define G_ 384   // 3*H

typedef _Float16 half8 __attribute__((ext_vector_type(8)));
typedef _Float16 half4v __attribute__((ext_vector_type(4)));
typedef float float4v __attribute__((ext_vector_type(4)));
typedef float float2v __attribute__((ext_vector_type(2)));

__device__ __forceinline__ float fsigmoid(float x){ return 1.0f/(1.0f+__expf(-x)); }
__device__ __forceinline__ float ftanh_(float x){ return 1.0f - 2.0f/(1.0f+__expf(2.0f*x)); }

// NOTE (R5-R7 post-mortem): inputs/outputs are f32 (reference is jnp.float32;
// R1's on-device {0,1}-mask detector confirmed). bf16 misread was the NaN bug.
//
// LDS-only barrier (R9: neutral vs __syncthreads; kept — guarantees no vmcnt
// drain). asm memory clobbers on BOTH sides pin LDS ops against the
// IntrNoMem s_barrier.
#define BAR() do{ asm volatile("s_waitcnt lgkmcnt(0)" ::: "memory"); \
                  __builtin_amdgcn_s_barrier(); \
                  asm volatile("" ::: "memory"); } while(0)

// wcol[b,j] = column sums of the row-normalized adjacency (R1 derivation).
// sim loop stays SCALAR with pitch 129 (odd pitch -> conflict-free broadcast).
__global__ void __launch_bounds__(256) adj_k(const float* mm, const float* E,
                                             float* wcol){
  int b = blockIdx.x;
  int tid = threadIdx.x;
  int d = tid & 63, q = tid >> 6;
  __shared__ float spp[4][64];
  __shared__ float sp[64];
  __shared__ float sE[64*129];
  __shared__ float ssim[64*65];
  __shared__ float srs[64];
  float p = 0.0f;
  for (int t = q*64; t < q*64+64; t++) p += 1.0f - mm[(b*T_ + t)*D_ + d];
  spp[q][d] = p;
  for (int i = tid; i < D_*H_; i += 256){ int r = i >> 7, c = i & 127; sE[r*129+c] = E[i]; }
  __syncthreads();
  if (tid < 64) sp[tid] = (spp[0][tid]+spp[1][tid]+spp[2][tid]+spp[3][tid]) * (1.0f/T_);
  __syncthreads();
  float rowE[128];
  #pragma unroll
  for (int k = 0; k < 128; k++) rowE[k] = sE[d*129+k];
  for (int i = q*16; i < q*16+16; i++){
    float s = 0.0f;
    #pragma unroll
    for (int k = 0; k < 128; k++) s += rowE[k]*sE[i*129+k];
    ssim[d*65+i] = fmaxf(s, 0.0f);
  }
  __syncthreads();
  if (tid < 64){
    float rs = 0.0f;
    for (int j = 0; j < 64; j++) rs += sp[j]*ssim[tid*65+j];
    srs[tid] = fmaxf(sp[tid]*rs + 1.0f, 1e-6f);
  }
  __syncthreads();
  if (tid < 64){
    float s = 0.0f;
    for (int i = 0; i < 64; i++) s += sp[i]*ssim[tid*65+i]/srs[i];
    wcol[b*64 + tid] = sp[tid]*s + 1.0f/srs[tid];
  }
}

// gi_k v5 (unchanged from R10): gi3 f16; E staged to LDS f16.
#define AVP 72
#define VRP 136
#define SEP 132
__global__ void __launch_bounds__(512,1) gi_k(const float* x, const float* mm,
                                              const float* vt, const float* E,
                                              const float* wih, const float* bih,
                                              const float* bhh, const float* wcol,
                                              _Float16* gi3){
  int bid = blockIdx.x;
  int b = bid >> 3, t0 = (bid & 7)*32;
  int tid = threadIdx.x;
  int w = tid >> 6, l = tid & 63;
  int lq = l >> 4, lm = l & 15;

  __shared__ __align__(16) _Float16 av[32*AVP];
  __shared__ __align__(16) _Float16 vrA[32*VRP];
  __shared__ __align__(16) _Float16 sEl[64*SEP];
  __shared__ float sVt[32];

  {
    int i = tid*4, t = i >> 6, d4 = i & 63;
    long src = (long)(b*T_ + t0 + t)*D_ + d4;
    float4 xv = *(const float4*)&x[src];
    float4 mv = *(const float4*)&mm[src];
    float4 wv = *(const float4*)&wcol[b*D_ + d4];
    half4v h;
    h[0]=(_Float16)(xv.x*(1.0f-mv.x)*wv.x*(1.0f/64));
    h[1]=(_Float16)(xv.y*(1.0f-mv.y)*wv.y*(1.0f/64));
    h[2]=(_Float16)(xv.z*(1.0f-mv.z)*wv.z*(1.0f/64));
    h[3]=(_Float16)(xv.w*(1.0f-mv.w)*wv.w*(1.0f/64));
    *(half4v*)&av[t*AVP + d4] = h;
  }
  {
    int r = tid >> 3, c0 = (tid & 7)*16;
    #pragma unroll
    for (int g = 0; g < 4; g++){
      float4 v = *(const float4*)&E[r*H_ + c0 + g*4];
      half4v h;
      h[0]=(_Float16)v.x; h[1]=(_Float16)v.y; h[2]=(_Float16)v.z; h[3]=(_Float16)v.w;
      *(half4v*)&sEl[r*SEP + c0 + g*4] = h;
    }
  }
  if (tid < 32) sVt[tid] = vt[b*T_ + t0 + tid];
  __syncthreads();

  half8 bE[2];
  #pragma unroll
  for (int kc = 0; kc < 2; kc++){
    half8 f;
    #pragma unroll
    for (int jj = 0; jj < 8; jj++)
      f[jj] = sEl[(kc*32 + lq*8 + jj)*SEP + 16*w + lm];
    bE[kc] = f;
  }

  float4v accA[2] = {{0,0,0,0},{0,0,0,0}};
  #pragma unroll
  for (int kc = 0; kc < 2; kc++){
    #pragma unroll
    for (int mt = 0; mt < 2; mt++){
      half8 a = *(const half8*)&av[(mt*16+lm)*AVP + kc*32 + lq*8];
      accA[mt] = __builtin_amdgcn_mfma_f32_16x16x32_f16(a, bE[kc], accA[mt], 0,0,0);
    }
  }
  {
    int h = 16*w + lm;
    float fr = __expf(-(float)(h & 63) * 0.14391157f);   // ln(1e4)/64
    #pragma unroll
    for (int mt = 0; mt < 2; mt++){
      #pragma unroll
      for (int r = 0; r < 4; r++){
        int tl = mt*16 + lq*4 + r;
        float ang = sVt[tl] * fr;
        float e = (h < 64) ? __sinf(ang) : __cosf(ang);
        vrA[tl*VRP + h] = (_Float16)(accA[mt][r] + e);
      }
    }
  }
  __syncthreads();

  half8 bW[3][4]; float biW[3];
  #pragma unroll
  for (int q = 0; q < 3; q++){
    int g = 16*(3*w + q) + lm;
    biW[q] = bih[g] + (g < 2*H_ ? bhh[g] : 0.0f);  // fold b_hh for r,z
    #pragma unroll
    for (int kc = 0; kc < 4; kc++){
      const float* src = &wih[(long)g*H_ + kc*32 + lq*8];
      float4 x0 = *(const float4*)src;
      float4 x1 = *(const float4*)(src+4);
      half8 f;
      f[0]=(_Float16)x0.x; f[1]=(_Float16)x0.y; f[2]=(_Float16)x0.z; f[3]=(_Float16)x0.w;
      f[4]=(_Float16)x1.x; f[5]=(_Float16)x1.y; f[6]=(_Float16)x1.z; f[7]=(_Float16)x1.w;
      bW[q][kc] = f;
    }
  }
  float4v cB[2][3];
  #pragma unroll
  for (int mt = 0; mt < 2; mt++)
    #pragma unroll
    for (int q = 0; q < 3; q++) cB[mt][q] = (float4v){0,0,0,0};
  #pragma unroll
  for (int kc = 0; kc < 4; kc++){
    #pragma unroll
    for (int mt = 0; mt < 2; mt++){
      half8 a = *(const half8*)&vrA[(mt*16+lm)*VRP + kc*32 + lq*8];
      #pragma unroll
      for (int q = 0; q < 3; q++)
        cB[mt][q] = __builtin_amdgcn_mfma_f32_16x16x32_f16(a, bW[q][kc], cB[mt][q], 0,0,0);
    }
  }
  #pragma unroll
  for (int mt = 0; mt < 2; mt++){
    #pragma unroll
    for (int q = 0; q < 3; q++){
      int g = 16*(3*w + q) + lm;
      int tb = t0 + mt*16 + lq*4;
      half4v hv;
      hv[0]=(_Float16)(cB[mt][q][0] + biW[q]); hv[1]=(_Float16)(cB[mt][q][1] + biW[q]);
      hv[2]=(_Float16)(cB[mt][q][2] + biW[q]); hv[3]=(_Float16)(cB[mt][q][3] + biW[q]);
      *(half4v*)&gi3[((long)(b*G_ + g))*T_ + tb] = hv;
    }
  }
}

// Sequential GRU v11: split-K across 8 waves (512 thr, 2 waves/SIMD).
// Wave w = (ww=w&3, kh=w>>2): same 6 N-tiles as R9's wave ww, but only
// K-half kh (2 kc chunks -> 12 MFMAs, 2 b128 A-frag reads; total DS b128
// stays 16/CU/step). Partials reduced via LDS float2(r,z)+float(n), gate
// lanes of waves 0-3 sum both halves and run the gates. 2 BARs/step.
__global__ void __launch_bounds__(512,1) gru_k(const _Float16* gi3, const float* whh,
                                               const float* bhh, const int* lengths,
                                               float* out){
  int b = blockIdx.x;
  int tid = threadIdx.x;
  int w = tid >> 6, l = tid & 63;
  int ww = w & 3, kh = w >> 2;
  int lq = l >> 4, lm = l & 15;
  int len = lengths[b];
  bool part = (l < 32);            // extraction lanes (all 8 waves)
  bool gate = part && (kh == 0);   // gate lanes (waves 0-3)
  int j = 32*ww + l;               // gate row when part

  __shared__ __align__(16) _Float16 hb[2][H_];
  __shared__ __align__(16) float2v ghrz[2][H_];   // [kh][j] = (r,z) partial
  __shared__ float ghn_[2][H_];                   // [kh][j] = n partial

  // B-frags: 6 tiles (2 per gate part) x this wave's 2 kc chunks.
  // tile i base = 32*ww + (i&1)*16 + (i>>1)*H_  (i: 0,1=r  2,3=z  4,5=n)
  half8 bfrag[6][2];
  #pragma unroll
  for (int i = 0; i < 6; i++){
    int row = 32*ww + (i>>1)*H_ + (i&1)*16 + lm;
    #pragma unroll
    for (int k2 = 0; k2 < 2; k2++){
      int kc = 2*kh + k2;
      const float* src = &whh[(long)row*H_ + kc*32 + lq*8];
      float4 x0 = *(const float4*)src;
      float4 x1 = *(const float4*)(src+4);
      half8 f;
      f[0]=(_Float16)x0.x; f[1]=(_Float16)x0.y; f[2]=(_Float16)x0.z; f[3]=(_Float16)x0.w;
      f[4]=(_Float16)x1.x; f[5]=(_Float16)x1.y; f[6]=(_Float16)x1.z; f[7]=(_Float16)x1.w;
      bfrag[i][k2] = f;
    }
  }
  float bn_ = 0.0f;
  const _Float16* pr = nullptr; const _Float16* pz; const _Float16* pn;
  if (gate){
    bn_ = bhh[2*H_ + j];
    pr = gi3 + ((long)b*G_ + j)*T_;
    pz = pr + (long)H_*T_;
    pn = pr + (long)2*H_*T_;
  }
  if (tid < H_){ hb[0][tid] = (_Float16)0.0f; hb[1][tid] = (_Float16)0.0f; }

  float gr[2][8], gz[2][8], gn[2][8];
  if (gate){
    half8 a = *(const half8*)(pr);
    half8 bv = *(const half8*)(pz);
    half8 cv = *(const half8*)(pn);
    #pragma unroll
    for (int i = 0; i < 8; i++){ gr[0][i]=(float)a[i]; gz[0][i]=(float)bv[i]; gn[0][i]=(float)cv[i]; }
  }
  __syncthreads();   // cold path

  float hval = 0.0f;
  float ho[8];
  int cb = 0;
  for (int c = 0; c < 32; c++){
    if (gate && c+1 < 32){
      int nb2 = (c+1)*8;
      half8 a = *(const half8*)(pr+nb2);
      half8 bv = *(const half8*)(pz+nb2);
      half8 cv = *(const half8*)(pn+nb2);
      int nc = cb^1;
      #pragma unroll
      for (int i = 0; i < 8; i++){ gr[nc][i]=(float)a[i]; gz[nc][i]=(float)bv[i]; gn[nc][i]=(float)cv[i]; }
    }
    #pragma unroll
    for (int i = 0; i < 8; i++){
      int rp = i & 1;            // read hb[rp], write hb[rp^1]
      // A-frags: this wave's K-half only
      half8 a0v = *(const half8*)&hb[rp][kh*64 + 0*32 + lq*8];
      half8 a1v = *(const half8*)&hb[rp][kh*64 + 1*32 + lq*8];
      float4v cc[6];
      #pragma unroll
      for (int q = 0; q < 6; q++) cc[q] = (float4v){0,0,0,0};
      #pragma unroll
      for (int q = 0; q < 6; q++) cc[q] = __builtin_amdgcn_mfma_f32_16x16x32_f16(a0v, bfrag[q][0], cc[q], 0,0,0);
      #pragma unroll
      for (int q = 0; q < 6; q++) cc[q] = __builtin_amdgcn_mfma_f32_16x16x32_f16(a1v, bfrag[q][1], cc[q], 0,0,0);
      if (part){
        float pr_ = (l & 16) ? cc[1][0] : cc[0][0];
        float pz_ = (l & 16) ? cc[3][0] : cc[2][0];
        float pn_ = (l & 16) ? cc[5][0] : cc[4][0];
        ghrz[kh][j] = (float2v){pr_, pz_};
        ghn_[kh][j] = pn_;
      }
      BAR();   // partials visible
      if (gate){
        float2v rz0 = ghrz[0][j], rz1 = ghrz[1][j];
        float n0 = ghn_[0][j],  n1 = ghn_[1][j];
        float r = fsigmoid(gr[cb][i] + rz0[0] + rz1[0]);
        float z = fsigmoid(gz[cb][i] + rz0[1] + rz1[1]);
        float n = ftanh_(gn[cb][i] + r*(n0 + n1 + bn_));
        hval = (1.0f - z)*n + z*hval;
        hb[rp^1][j] = (_Float16)hval;
        ho[i] = (c*8 + i < len) ? hval : 0.0f;
      }
      BAR();   // h visible
    }
    if (gate){
      long ob = ((long)b*T_ + c*8)*H_ + j;
      #pragma unroll
      for (int i = 0; i < 8; i++) out[ob + (long)i*H_] = ho[i];
    }
    cb ^= 1;
  }
}

extern "C" void kernel_launch(void* const* d_in, const int* in_sizes, int n_in,
                              void* d_out, int out_size, void* d_ws, size_t ws_size,
                              hipStream_t stream) {
  char* base = (char*)d_ws;
  size_t off = 0;
  auto alloc = [&](size_t bytes)->void*{
    void* p = base + off; off = (off + bytes + 255) & ~(size_t)255; return p;
  };
  float*     wcol = (float*)alloc((size_t)B_*D_*4);
  _Float16*  gi3  = (_Float16*)alloc((size_t)B_*G_*T_*2);
  if (off > ws_size) return;

  const float* x   = (const float*)d_in[0];
  const float* mm  = (const float*)d_in[1];
  const float* vt  = (const float*)d_in[2];
  const int*   len = (const int*)d_in[4];
  const float* E   = (const float*)d_in[5];
  const float* wih = (const float*)d_in[6];
  const float* whh = (const float*)d_in[7];
  const float* bih = (const float*)d_in[8];
  const float* bhh = (const float*)d_in[9];

  adj_k<<<dim3(B_),dim3(256),0,stream>>>(mm, E, wcol);
  gi_k<<<dim3(256),dim3(512),0,stream>>>(x, mm, vt, E, wih, bih, bhh, wcol, gi3);
  gru_k<<<dim3(B_),dim3(512),0,stream>>>(gi3, whh, bhh, len, (float*)d_out);
}

// Round 12
// 256.240 us; speedup vs baseline: 1.0461x; 1.0461x over previous
//
#include <hip/hip_runtime.h>
#include <hip/hip_bf16.h>

#define B_ 32
#define T_ 256
#define D_ 64
#define H_ 128
#define G_ 384   // 3*H

typedef _Float16 half8 __attribute__((ext_vector_type(8)));
typedef _Float16 half4v __attribute__((ext_vector_type(4)));
typedef float float4v __attribute__((ext_vector_type(4)));

__device__ __forceinline__ float fsigmoid(float x){ return 1.0f/(1.0f+__expf(-x)); }
__device__ __forceinline__ float ftanh_(float x){ return 1.0f - 2.0f/(1.0f+__expf(2.0f*x)); }

// NOTE (R5-R7 post-mortem): inputs/outputs are f32 (reference is jnp.float32;
// R1's on-device {0,1}-mask detector confirmed). bf16 misread was the NaN bug.
//
// Structure ledger (measured): R10's 1-barrier 4-wave chained-MFMA step is the
// minimum. R4 8-wave dup-K +19us; R8 chain-split +13us; R11 split-K 2-barrier
// +11us; R9 BAR vs __syncthreads neutral. Step ~1250 cyc vs ~466 cyc MFMA-issue
// floor (96 MFMAs/block/step, invariant under wave splits) + serial ds_read
// latency + gate transcendental chain + barrier — latency-bound recurrence.
#define BAR() do{ asm volatile("s_waitcnt lgkmcnt(0)" ::: "memory"); \
                  __builtin_amdgcn_s_barrier(); \
                  asm volatile("" ::: "memory"); } while(0)

// wcol[b,j] = column sums of the row-normalized adjacency (R1 derivation):
// adj_raw[i,j] = p_i p_j sim_ij + I; rs_i = 1 + p_i*sum_j p_j sim_ij;
// wcol_j = p_j * sum_i p_i sim_ij / rs_i + 1/rs_j  (sim symmetric).
// sim loop stays SCALAR with pitch 129: odd pitch puts the 4 quads' divergent
// i-rows on different banks -> conflict-free broadcast.
__global__ void __launch_bounds__(256) adj_k(const float* mm, const float* E,
                                             float* wcol){
  int b = blockIdx.x;
  int tid = threadIdx.x;
  int d = tid & 63, q = tid >> 6;
  __shared__ float spp[4][64];
  __shared__ float sp[64];
  __shared__ float sE[64*129];
  __shared__ float ssim[64*65];
  __shared__ float srs[64];
  float p = 0.0f;
  for (int t = q*64; t < q*64+64; t++) p += 1.0f - mm[(b*T_ + t)*D_ + d];
  spp[q][d] = p;
  for (int i = tid; i < D_*H_; i += 256){ int r = i >> 7, c = i & 127; sE[r*129+c] = E[i]; }
  __syncthreads();
  if (tid < 64) sp[tid] = (spp[0][tid]+spp[1][tid]+spp[2][tid]+spp[3][tid]) * (1.0f/T_);
  __syncthreads();
  float rowE[128];
  #pragma unroll
  for (int k = 0; k < 128; k++) rowE[k] = sE[d*129+k];
  for (int i = q*16; i < q*16+16; i++){
    float s = 0.0f;
    #pragma unroll
    for (int k = 0; k < 128; k++) s += rowE[k]*sE[i*129+k];
    ssim[d*65+i] = fmaxf(s, 0.0f);
  }
  __syncthreads();
  if (tid < 64){
    float rs = 0.0f;
    for (int j = 0; j < 64; j++) rs += sp[j]*ssim[tid*65+j];
    srs[tid] = fmaxf(sp[tid]*rs + 1.0f, 1e-6f);
  }
  __syncthreads();
  if (tid < 64){
    float s = 0.0f;
    for (int i = 0; i < 64; i++) s += sp[i]*ssim[tid*65+i]/srs[i];
    wcol[b*64 + tid] = sp[tid]*s + 1.0f/srs[tid];
  }
}

// gi_k v5: gi3 f16 (halves gi traffic); E staged into LDS f16 (pitch 132).
// Phase A: vr[32t][128h] = (x*(1-mm)*wcol/64)[32t][64d] x E[64d][128h] + time-enc
// Phase B: gi[32t][384g] = vr x W_ih^T + (bih + bhh[r,z]); gi3 transposed [b][g][t].
#define AVP 72
#define VRP 136
#define SEP 132
__global__ void __launch_bounds__(512,1) gi_k(const float* x, const float* mm,
                                              const float* vt, const float* E,
                                              const float* wih, const float* bih,
                                              const float* bhh, const float* wcol,
                                              _Float16* gi3){
  int bid = blockIdx.x;
  int b = bid >> 3, t0 = (bid & 7)*32;
  int tid = threadIdx.x;
  int w = tid >> 6, l = tid & 63;
  int lq = l >> 4, lm = l & 15;

  __shared__ __align__(16) _Float16 av[32*AVP];
  __shared__ __align__(16) _Float16 vrA[32*VRP];
  __shared__ __align__(16) _Float16 sEl[64*SEP];
  __shared__ float sVt[32];

  // stage av[t][d] = x*(1-mm)*wcol/64  (f32 in, f16 out)
  {
    int i = tid*4, t = i >> 6, d4 = i & 63;
    long src = (long)(b*T_ + t0 + t)*D_ + d4;
    float4 xv = *(const float4*)&x[src];
    float4 mv = *(const float4*)&mm[src];
    float4 wv = *(const float4*)&wcol[b*D_ + d4];
    half4v h;
    h[0]=(_Float16)(xv.x*(1.0f-mv.x)*wv.x*(1.0f/64));
    h[1]=(_Float16)(xv.y*(1.0f-mv.y)*wv.y*(1.0f/64));
    h[2]=(_Float16)(xv.z*(1.0f-mv.z)*wv.z*(1.0f/64));
    h[3]=(_Float16)(xv.w*(1.0f-mv.w)*wv.w*(1.0f/64));
    *(half4v*)&av[t*AVP + d4] = h;
  }
  // stage E -> LDS f16, coalesced
  {
    int r = tid >> 3, c0 = (tid & 7)*16;
    #pragma unroll
    for (int g = 0; g < 4; g++){
      float4 v = *(const float4*)&E[r*H_ + c0 + g*4];
      half4v h;
      h[0]=(_Float16)v.x; h[1]=(_Float16)v.y; h[2]=(_Float16)v.z; h[3]=(_Float16)v.w;
      *(half4v*)&sEl[r*SEP + c0 + g*4] = h;
    }
  }
  if (tid < 32) sVt[tid] = vt[b*T_ + t0 + tid];
  __syncthreads();

  // Phase A B-frags: B[k=d][n] = E[d][16w+n]  (gather from LDS)
  half8 bE[2];
  #pragma unroll
  for (int kc = 0; kc < 2; kc++){
    half8 f;
    #pragma unroll
    for (int jj = 0; jj < 8; jj++)
      f[jj] = sEl[(kc*32 + lq*8 + jj)*SEP + 16*w + lm];
    bE[kc] = f;
  }

  float4v accA[2] = {{0,0,0,0},{0,0,0,0}};
  #pragma unroll
  for (int kc = 0; kc < 2; kc++){
    #pragma unroll
    for (int mt = 0; mt < 2; mt++){
      half8 a = *(const half8*)&av[(mt*16+lm)*AVP + kc*32 + lq*8];
      accA[mt] = __builtin_amdgcn_mfma_f32_16x16x32_f16(a, bE[kc], accA[mt], 0,0,0);
    }
  }
  {
    int h = 16*w + lm;
    float fr = __expf(-(float)(h & 63) * 0.14391157f);   // ln(1e4)/64
    #pragma unroll
    for (int mt = 0; mt < 2; mt++){
      #pragma unroll
      for (int r = 0; r < 4; r++){
        int tl = mt*16 + lq*4 + r;
        float ang = sVt[tl] * fr;
        float e = (h < 64) ? __sinf(ang) : __cosf(ang);
        vrA[tl*VRP + h] = (_Float16)(accA[mt][r] + e);
      }
    }
  }
  __syncthreads();

  // Phase B: wave owns N-tiles 3w..3w+2
  half8 bW[3][4]; float biW[3];
  #pragma unroll
  for (int q = 0; q < 3; q++){
    int g = 16*(3*w + q) + lm;
    biW[q] = bih[g] + (g < 2*H_ ? bhh[g] : 0.0f);  // fold b_hh for r,z
    #pragma unroll
    for (int kc = 0; kc < 4; kc++){
      const float* src = &wih[(long)g*H_ + kc*32 + lq*8];
      float4 x0 = *(const float4*)src;
      float4 x1 = *(const float4*)(src+4);
      half8 f;
      f[0]=(_Float16)x0.x; f[1]=(_Float16)x0.y; f[2]=(_Float16)x0.z; f[3]=(_Float16)x0.w;
      f[4]=(_Float16)x1.x; f[5]=(_Float16)x1.y; f[6]=(_Float16)x1.z; f[7]=(_Float16)x1.w;
      bW[q][kc] = f;
    }
  }
  float4v cB[2][3];
  #pragma unroll
  for (int mt = 0; mt < 2; mt++)
    #pragma unroll
    for (int q = 0; q < 3; q++) cB[mt][q] = (float4v){0,0,0,0};
  #pragma unroll
  for (int kc = 0; kc < 4; kc++){
    #pragma unroll
    for (int mt = 0; mt < 2; mt++){
      half8 a = *(const half8*)&vrA[(mt*16+lm)*VRP + kc*32 + lq*8];
      #pragma unroll
      for (int q = 0; q < 3; q++)
        cB[mt][q] = __builtin_amdgcn_mfma_f32_16x16x32_f16(a, bW[q][kc], cB[mt][q], 0,0,0);
    }
  }
  #pragma unroll
  for (int mt = 0; mt < 2; mt++){
    #pragma unroll
    for (int q = 0; q < 3; q++){
      int g = 16*(3*w + q) + lm;
      int tb = t0 + mt*16 + lq*4;
      half4v hv;
      hv[0]=(_Float16)(cB[mt][q][0] + biW[q]); hv[1]=(_Float16)(cB[mt][q][1] + biW[q]);
      hv[2]=(_Float16)(cB[mt][q][2] + biW[q]); hv[3]=(_Float16)(cB[mt][q][3] + biW[q]);
      *(half4v*)&gi3[((long)(b*G_ + g))*T_ + tb] = hv;
    }
  }
}

// Sequential GRU v10 (measured best: 133.3 us): 4 waves, one LDS-only BAR per
// step, chained 4-deep MFMA accumulation, f16 gi3 prefetched 8 steps/chunk.
// Wave w owns 6 N-tiles (2 per gate part); gate lanes l<32 extract their
// triple via (l&16) select; h ping-pongs between two f16 LDS buffers.
__global__ void __launch_bounds__(256,1) gru_k(const _Float16* gi3, const float* whh,
                                               const float* bhh, const int* lengths,
                                               float* out){
  int b = blockIdx.x;
  int tid = threadIdx.x;
  int w = tid >> 6, l = tid & 63;
  int lq = l >> 4, lm = l & 15;
  int len = lengths[b];
  bool gate = (l < 32);
  int j = 32*w + l;              // gate index when gate==true

  __shared__ __align__(16) _Float16 hb[2][H_];

  // B-frags: tile i base {32w, 32w+16} + part*128 ; B[k][n] = W_hh[nb+n][k]
  half8 bfrag[6][4];
  #pragma unroll
  for (int i = 0; i < 6; i++){
    int row = 32*w + (i>>1)*H_ + (i&1)*16 + lm;
    #pragma unroll
    for (int kc = 0; kc < 4; kc++){
      const float* src = &whh[(long)row*H_ + kc*32 + lq*8];
      float4 x0 = *(const float4*)src;
      float4 x1 = *(const float4*)(src+4);
      half8 f;
      f[0]=(_Float16)x0.x; f[1]=(_Float16)x0.y; f[2]=(_Float16)x0.z; f[3]=(_Float16)x0.w;
      f[4]=(_Float16)x1.x; f[5]=(_Float16)x1.y; f[6]=(_Float16)x1.z; f[7]=(_Float16)x1.w;
      bfrag[i][kc] = f;
    }
  }
  float bn_ = 0.0f;
  const _Float16* pr = nullptr; const _Float16* pz; const _Float16* pn;
  if (gate){
    bn_ = bhh[2*H_ + j];
    pr = gi3 + ((long)b*G_ + j)*T_;
    pz = pr + (long)H_*T_;
    pn = pr + (long)2*H_*T_;
  }
  if (tid < H_){ hb[0][tid] = (_Float16)0.0f; hb[1][tid] = (_Float16)0.0f; }

  float gr[2][8], gz[2][8], gn[2][8];
  if (gate){
    half8 a = *(const half8*)(pr);
    half8 bv = *(const half8*)(pz);
    half8 cv = *(const half8*)(pn);
    #pragma unroll
    for (int i = 0; i < 8; i++){ gr[0][i]=(float)a[i]; gz[0][i]=(float)bv[i]; gn[0][i]=(float)cv[i]; }
  }
  __syncthreads();   // cold path: full barrier fine

  float hval = 0.0f;
  float ho[8];
  int cb = 0;
  for (int c = 0; c < 32; c++){
    if (gate && c+1 < 32){
      int nb2 = (c+1)*8;
      half8 a = *(const half8*)(pr+nb2);
      half8 bv = *(const half8*)(pz+nb2);
      half8 cv = *(const half8*)(pn+nb2);
      int nc = cb^1;
      #pragma unroll
      for (int i = 0; i < 8; i++){ gr[nc][i]=(float)a[i]; gz[nc][i]=(float)bv[i]; gn[nc][i]=(float)cv[i]; }
    }
    #pragma unroll
    for (int i = 0; i < 8; i++){
      int rp = i & 1;            // read hb[rp], write hb[rp^1]
      half8 a0v = *(const half8*)&hb[rp][0*32 + lq*8];
      half8 a1v = *(const half8*)&hb[rp][1*32 + lq*8];
      half8 a2v = *(const half8*)&hb[rp][2*32 + lq*8];
      half8 a3v = *(const half8*)&hb[rp][3*32 + lq*8];
      float4v cc[6];
      #pragma unroll
      for (int q = 0; q < 6; q++) cc[q] = (float4v){0,0,0,0};
      #pragma unroll
      for (int q = 0; q < 6; q++) cc[q] = __builtin_amdgcn_mfma_f32_16x16x32_f16(a0v, bfrag[q][0], cc[q], 0,0,0);
      #pragma unroll
      for (int q = 0; q < 6; q++) cc[q] = __builtin_amdgcn_mfma_f32_16x16x32_f16(a1v, bfrag[q][1], cc[q], 0,0,0);
      #pragma unroll
      for (int q = 0; q < 6; q++) cc[q] = __builtin_amdgcn_mfma_f32_16x16x32_f16(a2v, bfrag[q][2], cc[q], 0,0,0);
      #pragma unroll
      for (int q = 0; q < 6; q++) cc[q] = __builtin_amdgcn_mfma_f32_16x16x32_f16(a3v, bfrag[q][3], cc[q], 0,0,0);
      float ghr = (l & 16) ? cc[1][0] : cc[0][0];
      float ghz = (l & 16) ? cc[3][0] : cc[2][0];
      float ghn = (l & 16) ? cc[5][0] : cc[4][0];
      if (gate){
        float r = fsigmoid(gr[cb][i] + ghr);
        float z = fsigmoid(gz[cb][i] + ghz);
        float n = ftanh_(gn[cb][i] + r*(ghn + bn_));
        hval = (1.0f - z)*n + z*hval;
        hb[rp^1][j] = (_Float16)hval;
        ho[i] = (c*8 + i < len) ? hval : 0.0f;
      }
      BAR();
    }
    if (gate){
      long ob = ((long)b*T_ + c*8)*H_ + j;
      #pragma unroll
      for (int i = 0; i < 8; i++) out[ob + (long)i*H_] = ho[i];
    }
    cb ^= 1;
  }
}

extern "C" void kernel_launch(void* const* d_in, const int* in_sizes, int n_in,
                              void* d_out, int out_size, void* d_ws, size_t ws_size,
                              hipStream_t stream) {
  char* base = (char*)d_ws;
  size_t off = 0;
  auto alloc = [&](size_t bytes)->void*{
    void* p = base + off; off = (off + bytes + 255) & ~(size_t)255; return p;
  };
  float*     wcol = (float*)alloc((size_t)B_*D_*4);
  _Float16*  gi3  = (_Float16*)alloc((size_t)B_*G_*T_*2);
  if (off > ws_size) return;

  const float* x   = (const float*)d_in[0];
  const float* mm  = (const float*)d_in[1];
  const float* vt  = (const float*)d_in[2];
  const int*   len = (const int*)d_in[4];
  const float* E   = (const float*)d_in[5];
  const float* wih = (const float*)d_in[6];
  const float* whh = (const float*)d_in[7];
  const float* bih = (const float*)d_in[8];
  const float* bhh = (const float*)d_in[9];

  adj_k<<<dim3(B_),dim3(256),0,stream>>>(mm, E, wcol);
  gi_k<<<dim3(256),dim3(512),0,stream>>>(x, mm, vt, E, wih, bih, bhh, wcol, gi3);
  gru_k<<<dim3(B_),dim3(256),0,stream>>>(gi3, whh, bhh, len, (float*)d_out);
}